// Round 6
// baseline (154.718 us; speedup 1.0000x reference)
//
#include <hip/hip_runtime.h>

#define BATCH 256
#define TT 1024
#define NN 64
#define CHUNK 64
#define NCH 16
#define SOS 1
#define EOSI 2
#define LN2F 0.6931471805599453f
#define LOG2E 1.4426950408889634f

typedef short bf16x8 __attribute__((ext_vector_type(8)));
typedef float f32x4 __attribute__((ext_vector_type(4)));

__device__ __forceinline__ unsigned short f2bf(float x) {
  unsigned u = __float_as_uint(x);
  u += 0x7fffu + ((u >> 16) & 1u);
  return (unsigned short)(u >> 16);
}
__device__ __forceinline__ float bf2f(unsigned short v) { return __uint_as_float(((unsigned)v) << 16); }
__device__ __forceinline__ unsigned cvtpk(float lo, float hi) {
  unsigned r;
  asm("v_cvt_pk_bf16_f32 %0, %1, %2" : "=v"(r) : "v"(lo), "v"(hi));
  return r;
}

// Panel-local tiled address for (k = contraction row 0..63, c = local col 0..15), 2 KB.
// B-frag (Kc): addr = Kc*1024 + 16*lane  (lane-linear, conflict-free; layout validated R3-R5)
__device__ __forceinline__ int padr(int k, int c) {
  return ((k >> 5) << 10) + (((k >> 3) & 3) << 8) + (c << 4) + ((k & 7) << 1);
}

__device__ __forceinline__ int wave_len(const float* mask, int b, int l) {
  float ls = 0.f;
#pragma unroll
  for (int c = 0; c < 4; ++c) {
    float4 m4 = *reinterpret_cast<const float4*>(mask + (size_t)b * TT + c * 256 + l * 4);
    ls += (m4.x + m4.y) + (m4.z + m4.w);
  }
#pragma unroll
  for (int m = 1; m < 64; m <<= 1) ls += __shfl_xor(ls, m, 64);
  return (int)(ls + 0.5f);
}

// ---- Kernel A: 256 threads = 4 independent waves; wave w evolves column panel w of chunk (b,c) ----
__global__ __launch_bounds__(256, 4) void crf_chunk(const float* __restrict__ h,
                                                    const float* __restrict__ mask,
                                                    const float* __restrict__ trans,
                                                    unsigned short* __restrict__ mats,
                                                    int* __restrict__ scalesI) {
  __shared__ char lds[4 * 2048 + 4 * 512];  // 4 panels + 4 ping-pong ehs
  const int tid = threadIdx.x;
  const int w = tid >> 6;   // panel index = wave index
  const int l = tid & 63;
  const int h4 = l >> 4;
  const int cl = l & 15;
  char* P = lds + w * 2048;
  float* ehs0 = (float*)(lds + 8192 + w * 512);
  float* ehs1 = ehs0 + 64;

  const int b = blockIdx.x & (BATCH - 1);  // chunk-major grid
  const int c = blockIdx.x >> 8;

  const int len = wave_len(mask, b, l);
  const int t0 = c * CHUNK;
  if (t0 >= len) return;
  const int nstep = min(CHUNK, len - t0);

  // E fragments (A operand), layout validated R3-R5
  bf16x8 ef[4][2];
#pragma unroll
  for (int I = 0; I < 4; ++I)
#pragma unroll
    for (int Kc = 0; Kc < 2; ++Kc) {
      const float* p = trans + (16 * I + cl) * 64 + 32 * Kc + 8 * h4;
      bf16x8 v;
#pragma unroll
      for (int e = 0; e < 8; ++e) v[e] = (short)f2bf(__expf(p[e]));
      ef[I][Kc] = v;
    }

  // panel = identity columns 16w..16w+15
#pragma unroll
  for (int i = 0; i < 2; ++i) *(f32x4*)(P + ((i * 64 + l) << 4)) = f32x4{0.f, 0.f, 0.f, 0.f};
  if (l < 16) *(unsigned short*)(P + padr(16 * w + l, l)) = 0x3F80;  // bf16 1.0

  const float* hb = h + ((size_t)b * TT + t0) * NN + l;
  // ehs for step 0 (ec = 0)
  ehs0[l] = exp2f(hb[0] * LOG2E);
  asm volatile("" ::: "memory");  // same-wave DS ops are in-order; only pin program order

  float hvN = hb[(size_t)min(1, nstep - 1) * NN];   // h[t+1]
  float hvN2 = hb[(size_t)min(2, nstep - 1) * NN];  // h[t+2]
  int esum = 0, ecCur = 0, eM1 = 0;

  for (int t = 0; t < nstep; ++t) {
    // --- off-chain: prepare ehs for step t+1 (correction = measurement from end of t-1) ---
    esum += ecCur;
    float* ehsW = ((t + 1) & 1) ? ehs1 : ehs0;
    ehsW[l] = exp2f(fmaf(hvN, LOG2E, -(float)eM1));
    ecCur = eM1;
    hvN = hvN2;
    hvN2 = hb[(size_t)min(t + 3, nstep - 1) * NN];

    // --- chain: frag reads -> MFMA -> epilogue -> writes ---
    float* ehsR = (t & 1) ? ehs1 : ehs0;
    bf16x8 fc0 = *(bf16x8*)(P + (l << 4));
    bf16x8 fc1 = *(bf16x8*)(P + 1024 + (l << 4));
    f32x4 eh4[4];
#pragma unroll
    for (int I = 0; I < 4; ++I) eh4[I] = *(f32x4*)(ehsR + 16 * I + 4 * h4);

    f32x4 a[4];
#pragma unroll
    for (int I = 0; I < 4; ++I) a[I] = f32x4{0.f, 0.f, 0.f, 0.f};
#pragma unroll
    for (int I = 0; I < 4; ++I) {
      a[I] = __builtin_amdgcn_mfma_f32_16x16x32_bf16(ef[I][0], fc0, a[I], 0, 0, 0);
      a[I] = __builtin_amdgcn_mfma_f32_16x16x32_bf16(ef[I][1], fc1, a[I], 0, 0, 0);
    }
    float prox = 0.f;
#pragma unroll
    for (int I = 0; I < 4; ++I) {
      f32x4 v = a[I] * eh4[I];
      prox = fmaxf(prox, fmaxf(fmaxf(v[0], v[1]), fmaxf(v[2], v[3])));
      *(uint2*)(P + padr(16 * I + 4 * h4, cl)) = uint2{cvtpk(v[0], v[1]), cvtpk(v[2], v[3])};
    }
    // off-chain (used 2 steps later): full column max over h4 groups, col 5 proxy
    prox = fmaxf(prox, __shfl_xor(prox, 16, 64));
    prox = fmaxf(prox, __shfl_xor(prox, 32, 64));
    float px = __int_as_float(__builtin_amdgcn_readlane(__float_as_int(prox), 5));
    eM1 = (__float_as_int(px) >> 23) - 127;
    asm volatile("" ::: "memory");
  }

  // final exact pow2 renorm with latest measurement; row-major global store (one-time)
  const float scF = __int_as_float((127 - eM1) << 23);
  esum += eM1;
  unsigned short* gm = mats + (size_t)(b * NCH + c) * 4096 + l * 64 + 16 * w;
  unsigned q[8];
#pragma unroll
  for (int p = 0; p < 8; ++p) {
    float x0 = bf2f(*(unsigned short*)(P + padr(l, 2 * p))) * scF;
    float x1 = bf2f(*(unsigned short*)(P + padr(l, 2 * p + 1))) * scF;
    q[p] = cvtpk(x0, x1);
  }
  *(uint4*)gm = uint4{q[0], q[1], q[2], q[3]};
  *(uint4*)(gm + 8) = uint4{q[4], q[5], q[6], q[7]};
  if (l == 0) scalesI[(b * NCH + c) * 4 + w] = esum;
}

// ---- Kernel B: per-batch vector fold with per-panel exponent reconciliation ----
__global__ __launch_bounds__(64) void crf_fold(const float* __restrict__ mask,
                                               const float* __restrict__ trans,
                                               const unsigned short* __restrict__ mats,
                                               const int* __restrict__ scalesI,
                                               float* __restrict__ out) {
  __shared__ float pv[NN];
  const int l = threadIdx.x;
  const int b = blockIdx.x;
  const int len = wave_len(mask, b, l);
  const int nc = (len + CHUNK - 1) / CHUNK;

  float pr = (l == SOS) ? 1.f : 0.f;
  int eA = 0;
  long esumT = 0;

  for (int c = 0; c < nc; ++c) {
    const int* sI = scalesI + (b * NCH + c) * 4;
    const int e0 = sI[0], e1 = sI[1], e2 = sI[2], e3 = sI[3];
    const int S = max(max(e0, e1), max(e2, e3));
    const int g = l >> 4;
    int dl = (g == 0) ? e0 : (g == 1) ? e1 : (g == 2) ? e2 : e3;
    dl -= S;
    pv[l] = ldexpf(pr, dl - eA);  // per-source-column scale, pre-fold
    asm volatile("" ::: "memory");
    esumT += S + eA;

    const uint4* Mr = (const uint4*)(mats + (size_t)(b * NCH + c) * 4096 + l * 64);
    uint4 U[8];
#pragma unroll
    for (int j = 0; j < 8; ++j) U[j] = Mr[j];
    float ac0 = 0.f, ac1 = 0.f, ac2 = 0.f, ac3 = 0.f;
#pragma unroll
    for (int j = 0; j < 8; ++j) {
      f32x4 pa = *(f32x4*)(pv + j * 8);
      f32x4 pb = *(f32x4*)(pv + j * 8 + 4);
      uint4 qq = U[j];
      ac0 = fmaf(__uint_as_float(qq.x << 16), pa[0], ac0);
      ac1 = fmaf(__uint_as_float(qq.x & 0xffff0000u), pa[1], ac1);
      ac2 = fmaf(__uint_as_float(qq.y << 16), pa[2], ac2);
      ac3 = fmaf(__uint_as_float(qq.y & 0xffff0000u), pa[3], ac3);
      ac0 = fmaf(__uint_as_float(qq.z << 16), pb[0], ac0);
      ac1 = fmaf(__uint_as_float(qq.z & 0xffff0000u), pb[1], ac1);
      ac2 = fmaf(__uint_as_float(qq.w << 16), pb[2], ac2);
      ac3 = fmaf(__uint_as_float(qq.w & 0xffff0000u), pb[3], ac3);
    }
    pr = (ac0 + ac1) + (ac2 + ac3);
    float mm = pr;
#pragma unroll
    for (int m = 1; m < 64; m <<= 1) mm = fmaxf(mm, __shfl_xor(mm, m, 64));
    eA = (__float_as_int(mm) >> 23) - 127;  // applied next fold
    asm volatile("" ::: "memory");
  }

  float s = pr * __expf(trans[EOSI * NN + l]);
#pragma unroll
  for (int m = 1; m < 64; m <<= 1) s += __shfl_xor(s, m, 64);
  if (l == 0) out[b] = __logf(s) + LN2F * (float)esumT;
}

extern "C" void kernel_launch(void* const* d_in, const int* in_sizes, int n_in,
                              void* d_out, int out_size, void* d_ws, size_t ws_size,
                              hipStream_t stream) {
  const float* h = (const float*)d_in[0];
  const float* mask = (const float*)d_in[1];
  const float* trans = (const float*)d_in[2];
  float* out = (float*)d_out;

  unsigned short* mats = (unsigned short*)d_ws;  // 32 MB
  int* scalesI = (int*)((char*)d_ws + (size_t)BATCH * NCH * 4096 * 2);  // +64 KB

  hipLaunchKernelGGL(crf_chunk, dim3(BATCH * NCH), dim3(256), 0, stream, h, mask, trans, mats, scalesI);
  hipLaunchKernelGGL(crf_fold, dim3(BATCH), dim3(64), 0, stream, mask, trans, mats, scalesI, out);
}